// Round 2
// baseline (1296.289 us; speedup 1.0000x reference)
//
#include <hip/hip_runtime.h>

typedef float v2f __attribute__((ext_vector_type(2)));

#define T_LEN 2048
#define NH    10
#define OUT_T 1439
#define TFIRST 608      // first output timestep (T - TAIL)
#define NSEQ  4096

static __device__ __forceinline__ v2f fma2(v2f a, v2f b, v2f c) {
  return __builtin_elementwise_fma(a, b, c);
}
static __device__ __forceinline__ v2f splat2(float v) { v2f r; r.x = v; r.y = v; return r; }

// sigmoid(z) = rcp(1 + exp2(z * -log2(e)))
static __device__ __forceinline__ float fast_sigmoid(float z) {
  float e = __builtin_amdgcn_exp2f(z * -1.4426950408889634f);
  return __builtin_amdgcn_rcpf(1.0f + e);
}
// tanh(z) = 2*sigmoid(2z) - 1 ; overflow -> Inf -> rcp -> 0 -> -1 (saturates correctly)
static __device__ __forceinline__ float fast_tanh(float z) {
  float e = __builtin_amdgcn_exp2f(z * -2.8853900817779268f);
  return __builtin_amdgcn_rcpf(1.0f + e) * 2.0f - 1.0f;
}

// DPP row_ror:N within rows of 16: dest[i] = src[(i-N)&15] (row_shr-reduce-idiom direction)
#define ROR_F(v, N) __uint_as_float(__builtin_amdgcn_update_dpp( \
    0, (int)__float_as_uint(v), 0x120 + (N), 0xF, 0xF, true))

// 4 sequences per wave; 16 lanes (one DPP row) per sequence; lane u<10 owns
// hidden unit u (all 4 gates). Lanes u=10..15 carry fc1 rows folded into the
// layer-1 "g" gate slot of the h1-recurrent ring. All cross-lane traffic is
// DPP (VALU) — zero LDS, zero lgkmcnt on the critical chain.
__global__ void __launch_bounds__(64, 1)
lstm_fused(const float* __restrict__ x,
           const float* __restrict__ w_ih0, const float* __restrict__ w_hh0,
           const float* __restrict__ b_ih0, const float* __restrict__ b_hh0,
           const float* __restrict__ w_ih1, const float* __restrict__ w_hh1,
           const float* __restrict__ b_ih1, const float* __restrict__ b_hh1,
           const float* __restrict__ fc1_w, const float* __restrict__ fc1_b,
           const float* __restrict__ fc2_w, const float* __restrict__ fc2_b,
           float* __restrict__ out)
{
  const int lane = threadIdx.x;       // 0..63
  const int grp  = lane >> 4;         // sequence within wave (0..3) == DPP row
  const int u    = lane & 15;         // unit slot within group
  const int seq  = (int)blockIdx.x * 4 + grp;

  // Pre-rotated per-lane weights: index k means "multiplies h[(u-k)&15]".
  v2f w0if[16], w0go[16];     // layer0 h0-recurrent, gates (i,f) and (g,o)
  v2f w1hif[16], w1hgo[16];   // layer1 h1-recurrent (go.x carries fc1 on pad lanes)
  v2f w1iif[16], w1igo[16];   // layer1 h0-input
  v2f b0_if, b0_go, b1_if, b1_go, wx_if, wx_go;
  b0_if = b0_go = b1_if = b1_go = wx_if = wx_go = splat2(0.f);

  if (u < NH) {
    const int ri = 0*NH+u, rf = 1*NH+u, rg = 2*NH+u, ro = 3*NH+u;
    wx_if.x = w_ih0[ri]; wx_if.y = w_ih0[rf];
    wx_go.x = w_ih0[rg]; wx_go.y = w_ih0[ro];
    b0_if.x = b_ih0[ri] + b_hh0[ri]; b0_if.y = b_ih0[rf] + b_hh0[rf];
    b0_go.x = b_ih0[rg] + b_hh0[rg]; b0_go.y = b_ih0[ro] + b_hh0[ro];
    b1_if.x = b_ih1[ri] + b_hh1[ri]; b1_if.y = b_ih1[rf] + b_hh1[rf];
    b1_go.x = b_ih1[rg] + b_hh1[rg]; b1_go.y = b_ih1[ro] + b_hh1[ro];
  } else {
    b1_go.x = fc1_b[u - NH];          // fc1 bias in the L1 "g" slot (gets tanh)
  }

#pragma unroll
  for (int k = 0; k < 16; ++k) {
    const int j = (u - k) & 15;
    const bool v = (j < NH);
    v2f z = splat2(0.f);
    w0if[k] = z; w0go[k] = z; w1hif[k] = z; w1hgo[k] = z; w1iif[k] = z; w1igo[k] = z;
    if (u < NH) {
      if (v) {
        const int ri = 0*NH+u, rf = 1*NH+u, rg = 2*NH+u, ro = 3*NH+u;
        w0if[k].x = w_hh0[ri*NH+j]; w0if[k].y = w_hh0[rf*NH+j];
        w0go[k].x = w_hh0[rg*NH+j]; w0go[k].y = w_hh0[ro*NH+j];
        w1hif[k].x = w_hh1[ri*NH+j]; w1hif[k].y = w_hh1[rf*NH+j];
        w1hgo[k].x = w_hh1[rg*NH+j]; w1hgo[k].y = w_hh1[ro*NH+j];
        w1iif[k].x = w_ih1[ri*NH+j]; w1iif[k].y = w_ih1[rf*NH+j];
        w1igo[k].x = w_ih1[rg*NH+j]; w1igo[k].y = w_ih1[ro*NH+j];
      }
    } else {
      if (v) w1hgo[k].x = fc1_w[(u - NH)*NH + j];   // fc1 acts on h1(t-1)
    }
  }

  const float fc2wl = (u >= NH) ? fc2_w[u - NH] : 0.f;
  const float fc2bl = fc2_b[0];

  const float* xp   = x + (size_t)seq * T_LEN;
  float*       outp = out + (size_t)seq * OUT_T;

  float c0 = 0.f, c1 = 0.f, h0p = 0.f, h1p = 0.f;
  float xv = xp[0];

#pragma unroll 1
  for (int t = 0; t < T_LEN; ++t) {
    const int tn = (t + 1 < T_LEN) ? (t + 1) : (T_LEN - 1);
    const float xn = xp[tn];                       // prefetch next x

    // Dual accumulators (even/odd k) per gate-pair to halve the FMA dep chain.
    v2f a0if[2], a0go[2], a1if[2], a1go[2];
    a0if[0] = fma2(wx_if, splat2(xv), b0_if);  a0if[1] = splat2(0.f);
    a0go[0] = fma2(wx_go, splat2(xv), b0_go);  a0go[1] = splat2(0.f);
    a1if[0] = b1_if;                           a1if[1] = splat2(0.f);
    a1go[0] = b1_go;                           a1go[1] = splat2(0.f);

    // ---- ring AB: h0(t-1) feeds L0 gates; h1(t-1) feeds L1 recurrent (+fc1) ----
#define RAB(K, P) { \
    const float h0j = (K) ? ROR_F(h0p, (K) ? (K) : 1) : h0p; \
    const float h1j = (K) ? ROR_F(h1p, (K) ? (K) : 1) : h1p; \
    a0if[P] = fma2(w0if[K],  splat2(h0j), a0if[P]); \
    a0go[P] = fma2(w0go[K],  splat2(h0j), a0go[P]); \
    a1if[P] = fma2(w1hif[K], splat2(h1j), a1if[P]); \
    a1go[P] = fma2(w1hgo[K], splat2(h1j), a1go[P]); }
    RAB(0,0)  RAB(1,1)  RAB(2,0)  RAB(3,1)
    RAB(4,0)  RAB(5,1)  RAB(6,0)  RAB(7,1)
    RAB(8,0)  RAB(9,1)  RAB(10,0) RAB(11,1)
    RAB(12,0) RAB(13,1) RAB(14,0) RAB(15,1)
#undef RAB

    // ---- layer 0 activations ----
    const v2f g0if = a0if[0] + a0if[1];
    const v2f g0go = a0go[0] + a0go[1];
    const float si = fast_sigmoid(g0if.x);
    const float sf = fast_sigmoid(g0if.y);
    const float tg = fast_tanh(g0go.x);
    const float so = fast_sigmoid(g0go.y);
    c0 = sf * c0 + si * tg;
    const float h0n = so * fast_tanh(c0);          // pad lanes: exactly 0

    // ---- ring C: h0(t) feeds L1 input gates ----
#define RC(K, P) { \
    const float hj = (K) ? ROR_F(h0n, (K) ? (K) : 1) : h0n; \
    a1if[P] = fma2(w1iif[K], splat2(hj), a1if[P]); \
    a1go[P] = fma2(w1igo[K], splat2(hj), a1go[P]); }
    RC(0,0)  RC(1,1)  RC(2,0)  RC(3,1)
    RC(4,0)  RC(5,1)  RC(6,0)  RC(7,1)
    RC(8,0)  RC(9,1)  RC(10,0) RC(11,1)
    RC(12,0) RC(13,1) RC(14,0) RC(15,1)
#undef RC

    // ---- layer 1 activations ----
    const v2f g1if = a1if[0] + a1if[1];
    const v2f g1go = a1go[0] + a1go[1];
    const float si1 = fast_sigmoid(g1if.x);
    const float sf1 = fast_sigmoid(g1if.y);
    const float tg1 = fast_tanh(g1go.x);           // pad lanes: tanh(fc1(h1_{t-1}))
    const float so1 = fast_sigmoid(g1go.y);
    c1 = sf1 * c1 + si1 * tg1;
    const float h1n = so1 * fast_tanh(c1);         // pad lanes harmless (zero weights)

    // ---- fc2: output for timestep t-1 (VALU-only DPP row reduce) ----
    if (t > TFIRST) {                              // t in [609, 2047] -> out idx 0..1438
      float y = tg1 * fc2wl;                       // zero on lanes u<10
      y += ROR_F(y, 8);
      y += ROR_F(y, 4);
      y += ROR_F(y, 2);
      y += ROR_F(y, 1);                            // all 16 lanes now hold row sum
      if (u == 0) outp[t - 1 - TFIRST] = y + fc2bl;
    }

    h0p = h0n; h1p = h1n;
    xv = xn;
  }
}

extern "C" void kernel_launch(void* const* d_in, const int* in_sizes, int n_in,
                              void* d_out, int out_size, void* d_ws, size_t ws_size,
                              hipStream_t stream) {
  const float* x     = (const float*)d_in[0];
  const float* w_ih0 = (const float*)d_in[1];
  const float* w_hh0 = (const float*)d_in[2];
  const float* b_ih0 = (const float*)d_in[3];
  const float* b_hh0 = (const float*)d_in[4];
  const float* w_ih1 = (const float*)d_in[5];
  const float* w_hh1 = (const float*)d_in[6];
  const float* b_ih1 = (const float*)d_in[7];
  const float* b_hh1 = (const float*)d_in[8];
  const float* fc1_w = (const float*)d_in[9];
  const float* fc1_b = (const float*)d_in[10];
  const float* fc2_w = (const float*)d_in[11];
  const float* fc2_b = (const float*)d_in[12];
  float* out = (float*)d_out;

  lstm_fused<<<dim3(NSEQ / 4), dim3(64), 0, stream>>>(
      x, w_ih0, w_hh0, b_ih0, b_hh0, w_ih1, w_hh1, b_ih1, b_hh1,
      fc1_w, fc1_b, fc2_w, fc2_b, out);
}

// Round 3
// 1103.450 us; speedup vs baseline: 1.1748x; 1.1748x over previous
//
#include <hip/hip_runtime.h>

typedef float v2f __attribute__((ext_vector_type(2)));

#define T_LEN 2048
#define NH    10
#define OUT_T 1439
#define TFIRST 608      // first output timestep (T - TAIL)
#define NSEQ  4096

static __device__ __forceinline__ v2f fma2(v2f a, v2f b, v2f c) {
  return __builtin_elementwise_fma(a, b, c);
}
static __device__ __forceinline__ v2f splat2(float v) { v2f r; r.x = v; r.y = v; return r; }
static __device__ __forceinline__ v2f mulsp(v2f a, float s) { v2f r; r.x = a.x*s; r.y = a.y*s; return r; }

// sigmoid(z) = rcp(1 + exp2(z * -log2(e)))
static __device__ __forceinline__ float fast_sigmoid(float z) {
  float e = __builtin_amdgcn_exp2f(z * -1.4426950408889634f);
  return __builtin_amdgcn_rcpf(1.0f + e);
}
// tanh(z) = 2*sigmoid(2z) - 1 ; overflow -> Inf -> rcp -> 0 -> -1 (saturates)
static __device__ __forceinline__ float fast_tanh(float z) {
  float e = __builtin_amdgcn_exp2f(z * -2.8853900817779268f);
  return __builtin_amdgcn_rcpf(1.0f + e) * 2.0f - 1.0f;
}

// Broadcast lane (row*16 + j) to all lanes of its 16-row, via ds_swizzle
// BitMode: src = ((i & 0x10) | j) within each 32-half. Lane crossbar only —
// no LDS storage, no bank conflicts. Each of the 4 rows (4 seqs) reads its
// own seq's h[j].
#define SWZB(v, j) __uint_as_float(__builtin_amdgcn_ds_swizzle( \
    (int)__float_as_uint(v), (((j) << 5) | 0x10)))

// DPP row_ror:N within rows of 16 (verified in R1): dest[i] = src[(i-N)&15]
#define ROR_F(v, N) __uint_as_float(__builtin_amdgcn_update_dpp( \
    0, (int)__float_as_uint(v), 0x120 + (N), 0xF, 0xF, true))

// 4 sequences per wave; 16 lanes per sequence; lane u<10 owns hidden unit u
// (all four gates, packed (i,f)/(g,o) in v2f). Lanes u=10..15 carry fc1 rows
// folded into the layer-1 "g" slot (which receives tanh) — FC head is free.
// All h-broadcast via ds_swizzle (no LDS round trip), fc2 via DPP ror reduce.
__global__ void __launch_bounds__(64, 1)
lstm_fused(const float* __restrict__ x,
           const float* __restrict__ w_ih0, const float* __restrict__ w_hh0,
           const float* __restrict__ b_ih0, const float* __restrict__ b_hh0,
           const float* __restrict__ w_ih1, const float* __restrict__ w_hh1,
           const float* __restrict__ b_ih1, const float* __restrict__ b_hh1,
           const float* __restrict__ fc1_w, const float* __restrict__ fc1_b,
           const float* __restrict__ fc2_w, const float* __restrict__ fc2_b,
           float* __restrict__ out)
{
  const int lane = threadIdx.x;       // 0..63
  const int grp  = lane >> 4;         // sequence within wave (0..3) == 16-row
  const int u    = lane & 15;         // unit slot within group
  const int seq  = (int)blockIdx.x * 4 + grp;

  v2f whh0_if[NH], whh0_go[NH], wih1_if[NH], wih1_go[NH], whh1_if[NH], whh1_go[NH];
  v2f b0_if, b0_go, b1_if, b1_go, wx_if, wx_go;
  b0_if = b0_go = b1_if = b1_go = wx_if = wx_go = splat2(0.f);
#pragma unroll
  for (int j = 0; j < NH; ++j) {
    whh0_if[j] = splat2(0.f); whh0_go[j] = splat2(0.f);
    wih1_if[j] = splat2(0.f); wih1_go[j] = splat2(0.f);
    whh1_if[j] = splat2(0.f); whh1_go[j] = splat2(0.f);
  }

  if (u < NH) {
    const int ri = 0*NH+u, rf = 1*NH+u, rg = 2*NH+u, ro = 3*NH+u;
    wx_if.x = w_ih0[ri]; wx_if.y = w_ih0[rf];
    wx_go.x = w_ih0[rg]; wx_go.y = w_ih0[ro];
    b0_if.x = b_ih0[ri] + b_hh0[ri]; b0_if.y = b_ih0[rf] + b_hh0[rf];
    b0_go.x = b_ih0[rg] + b_hh0[rg]; b0_go.y = b_ih0[ro] + b_hh0[ro];
    b1_if.x = b_ih1[ri] + b_hh1[ri]; b1_if.y = b_ih1[rf] + b_hh1[rf];
    b1_go.x = b_ih1[rg] + b_hh1[rg]; b1_go.y = b_ih1[ro] + b_hh1[ro];
#pragma unroll
    for (int j = 0; j < NH; ++j) {
      whh0_if[j].x = w_hh0[ri*NH+j]; whh0_if[j].y = w_hh0[rf*NH+j];
      whh0_go[j].x = w_hh0[rg*NH+j]; whh0_go[j].y = w_hh0[ro*NH+j];
      wih1_if[j].x = w_ih1[ri*NH+j]; wih1_if[j].y = w_ih1[rf*NH+j];
      wih1_go[j].x = w_ih1[rg*NH+j]; wih1_go[j].y = w_ih1[ro*NH+j];
      whh1_if[j].x = w_hh1[ri*NH+j]; whh1_if[j].y = w_hh1[rf*NH+j];
      whh1_go[j].x = w_hh1[rg*NH+j]; whh1_go[j].y = w_hh1[ro*NH+j];
    }
  } else {
    b1_go.x = fc1_b[u - NH];          // fc1 bias in the L1 "g" slot (gets tanh)
#pragma unroll
    for (int j = 0; j < NH; ++j) whh1_go[j].x = fc1_w[(u - NH)*NH + j];
  }

  const float fc2wl = (u >= NH) ? fc2_w[u - NH] : 0.f;
  const float fc2bl = fc2_b[0];

  const float* xp   = x + (size_t)seq * T_LEN;
  float*       outp = out + (size_t)seq * OUT_T;

  float c0 = 0.f, c1 = 0.f, h0p = 0.f, h1p = 0.f;
  float xv = xp[0];

#pragma unroll 1
  for (int t = 0; t < T_LEN; ++t) {
    const int tn = (t + 1 < T_LEN) ? (t + 1) : (T_LEN - 1);
    const float xn = xp[tn];                       // prefetch next x

    // ---- issue all h-broadcasts up front (independent crossbar ops) ----
    const float p0 = SWZB(h0p,0), p1 = SWZB(h0p,1), p2 = SWZB(h0p,2),
                p3 = SWZB(h0p,3), p4 = SWZB(h0p,4), p5 = SWZB(h0p,5),
                p6 = SWZB(h0p,6), p7 = SWZB(h0p,7), p8 = SWZB(h0p,8),
                p9 = SWZB(h0p,9);
    const float q0 = SWZB(h1p,0), q1 = SWZB(h1p,1), q2 = SWZB(h1p,2),
                q3 = SWZB(h1p,3), q4 = SWZB(h1p,4), q5 = SWZB(h1p,5),
                q6 = SWZB(h1p,6), q7 = SWZB(h1p,7), q8 = SWZB(h1p,8),
                q9 = SWZB(h1p,9);

    // ---- layer 0 gates (dual accumulators) ----
    v2f aA = fma2(wx_if, splat2(xv), b0_if);
    v2f gA = fma2(wx_go, splat2(xv), b0_go);
    v2f aB = mulsp(whh0_if[1], p1);
    v2f gB = mulsp(whh0_go[1], p1);
#define L0T(j, hv, AA, GG) { const v2f s = splat2(hv); \
    AA = fma2(whh0_if[j], s, AA); GG = fma2(whh0_go[j], s, GG); }
    L0T(0, p0, aA, gA)  L0T(2, p2, aA, gA)  L0T(3, p3, aB, gB)
    L0T(4, p4, aA, gA)  L0T(5, p5, aB, gB)  L0T(6, p6, aA, gA)
    L0T(7, p7, aB, gB)  L0T(8, p8, aA, gA)  L0T(9, p9, aB, gB)
#undef L0T
    const v2f g0if = aA + aB;
    const v2f g0go = gA + gB;

    // ---- layer 1 h1-recurrent part (+fc1), independent of layer-0 acts ----
    v2f bA = fma2(whh1_if[0], splat2(q0), b1_if);
    v2f hA = fma2(whh1_go[0], splat2(q0), b1_go);
    v2f bB = mulsp(whh1_if[1], q1);
    v2f hB = mulsp(whh1_go[1], q1);
#define L1R(j, hv, AA, GG) { const v2f s = splat2(hv); \
    AA = fma2(whh1_if[j], s, AA); GG = fma2(whh1_go[j], s, GG); }
    L1R(2, q2, bA, hA)  L1R(3, q3, bB, hB)  L1R(4, q4, bA, hA)
    L1R(5, q5, bB, hB)  L1R(6, q6, bA, hA)  L1R(7, q7, bB, hB)
    L1R(8, q8, bA, hA)  L1R(9, q9, bB, hB)
#undef L1R

    // ---- layer 0 activations ----
    const float si = fast_sigmoid(g0if.x);
    const float sf = fast_sigmoid(g0if.y);
    const float tg = fast_tanh(g0go.x);
    const float so = fast_sigmoid(g0go.y);
    c0 = sf * c0 + si * tg;
    const float h0n = so * fast_tanh(c0);          // pad lanes: finite garbage, never read

    // ---- broadcast h0(t), finish layer 1 gates ----
    const float r0 = SWZB(h0n,0), r1 = SWZB(h0n,1), r2 = SWZB(h0n,2),
                r3 = SWZB(h0n,3), r4 = SWZB(h0n,4), r5 = SWZB(h0n,5),
                r6 = SWZB(h0n,6), r7 = SWZB(h0n,7), r8 = SWZB(h0n,8),
                r9 = SWZB(h0n,9);
#define L1I(j, hv, AA, GG) { const v2f s = splat2(hv); \
    AA = fma2(wih1_if[j], s, AA); GG = fma2(wih1_go[j], s, GG); }
    L1I(0, r0, bA, hA)  L1I(1, r1, bB, hB)  L1I(2, r2, bA, hA)
    L1I(3, r3, bB, hB)  L1I(4, r4, bA, hA)  L1I(5, r5, bB, hB)
    L1I(6, r6, bA, hA)  L1I(7, r7, bB, hB)  L1I(8, r8, bA, hA)
    L1I(9, r9, bB, hB)
#undef L1I
    const v2f g1if = bA + bB;
    const v2f g1go = hA + hB;

    // ---- layer 1 activations ----
    const float si1 = fast_sigmoid(g1if.x);
    const float sf1 = fast_sigmoid(g1if.y);
    const float tg1 = fast_tanh(g1go.x);           // fc lanes: tanh(fc1(h1_{t-1}))
    const float so1 = fast_sigmoid(g1go.y);
    c1 = sf1 * c1 + si1 * tg1;
    const float h1n = so1 * fast_tanh(c1);

    // ---- fc2: output for timestep t-1 (VALU-only DPP row reduce) ----
    if (t > TFIRST) {                              // t in [609, 2047] -> out idx 0..1438
      float y = tg1 * fc2wl;                       // zero on lanes u<10
      y += ROR_F(y, 8);
      y += ROR_F(y, 4);
      y += ROR_F(y, 2);
      y += ROR_F(y, 1);                            // all 16 lanes hold row sum
      if (u == 0) outp[t - 1 - TFIRST] = y + fc2bl;
    }

    h0p = h0n; h1p = h1n;
    xv = xn;
  }
}

extern "C" void kernel_launch(void* const* d_in, const int* in_sizes, int n_in,
                              void* d_out, int out_size, void* d_ws, size_t ws_size,
                              hipStream_t stream) {
  const float* x     = (const float*)d_in[0];
  const float* w_ih0 = (const float*)d_in[1];
  const float* w_hh0 = (const float*)d_in[2];
  const float* b_ih0 = (const float*)d_in[3];
  const float* b_hh0 = (const float*)d_in[4];
  const float* w_ih1 = (const float*)d_in[5];
  const float* w_hh1 = (const float*)d_in[6];
  const float* b_ih1 = (const float*)d_in[7];
  const float* b_hh1 = (const float*)d_in[8];
  const float* fc1_w = (const float*)d_in[9];
  const float* fc1_b = (const float*)d_in[10];
  const float* fc2_w = (const float*)d_in[11];
  const float* fc2_b = (const float*)d_in[12];
  float* out = (float*)d_out;

  lstm_fused<<<dim3(NSEQ / 4), dim3(64), 0, stream>>>(
      x, w_ih0, w_hh0, b_ih0, b_hh0, w_ih1, w_hh1, b_ih1, b_hh1,
      fc1_w, fc1_b, fc2_w, fc2_b, out);
}